// Round 9
// baseline (543.328 us; speedup 1.0000x reference)
//
#include <hip/hip_runtime.h>
#include <hip/hip_cooperative_groups.h>

namespace cg = cooperative_groups;

// SimpleSelfAttention: B=4, S=2048, D=1024, fp32 in/out, bf16 MFMA internally.
// R17 = single cooperative kernel fusing prep -> qkv -> scores -> pv with
//       grid syncs (eliminates 3 dispatch boundaries; grid-strided prep fixes
//       the 11272-tiny-block launch shape). All GEMM bodies byte-identical to
//       R16 (measured-stable). Vt tiles pulled from a device-global atomic
//       queue to reproduce the HW dispatcher's dynamic balancing. 256 blocks
//       x 512 threads, 160KB LDS, exactly 1 block/CU (max co-residency).
//       Fallback: if cooperative launch errors, run the R16 4-dispatch path.

typedef __attribute__((ext_vector_type(8))) short short8;
typedef __attribute__((ext_vector_type(4))) short short4v;
typedef __attribute__((ext_vector_type(4))) float float4v;

__device__ __forceinline__ short f2bf(float f) {
  unsigned u = __builtin_bit_cast(unsigned, f);
  u += 0x7fffu + ((u >> 16) & 1u);  // RNE; inputs finite
  return (short)(u >> 16);
}
__device__ __forceinline__ float bf2f(short s) {
  unsigned u = ((unsigned)(unsigned short)s) << 16;
  return __builtin_bit_cast(float, u);
}

// async global->LDS, 16B per lane. LDS dest = wave-uniform base + lane*16.
__device__ __forceinline__ void gl2lds16(const void* g, void* l) {
  __builtin_amdgcn_global_load_lds((const __attribute__((address_space(1))) void*)g,
                                   (__attribute__((address_space(3))) void*)l, 16, 0, 0);
}

__device__ unsigned g_vt_ctr;   // Vt tile queue (zeroed in phase 0 each launch)

// ---------- staging: one 128x64 bf16 half-tile, 2 x global_load_lds per thread ----
// LDS layout per row r (128 B): 16B chunk slot s holds global chunk s ^ (r&7).
__device__ __forceinline__ void stage_half(const short* __restrict__ g, int ld,
                                           int grow0, int kt, short* lds, int t) {
  const int r = t >> 3;                         // 0..63
  const int cch = (t & 7) ^ (r & 7);            // global chunk for this slot
  const long co = (long)kt + cch * 8;
  gl2lds16(g + (long)(grow0 + r) * ld + co, lds + t * 8);
  gl2lds16(g + (long)(grow0 + 64 + r) * ld + co, lds + 4096 + t * 8);
}

// ---------- shared GEMM body: C[m,n] = sum_k A[m,k]*B[n,k], BK=64 ----
// (byte-identical schedule to R16; see R11/R12 notes for the safety argument)
template <int EPI, int MH>
__device__ __forceinline__ void gemm_body(const short* __restrict__ A,
                                          const short* __restrict__ Bm,
                                          void* __restrict__ C,
                                          const float* __restrict__ aux,
                                          float* __restrict__ rsum, float scale,
                                          int N, int Kd, int Bld, int m0, int n0,
                                          short (*As)[64], short (*Bs)[64]) {
  const int t = threadIdx.x;
  const int lane = t & 63;
  const int wave = t >> 6;               // 0..7
  const int wm = (wave >> 2) * 64 * MH;  // MH=2: 0/128; MH=1: 0/64
  const int wn = (wave & 3) * 64;        // 0,64,128,192
  const int col = lane & 15, quad = lane >> 4;
  const int sw = col & 7;                // reader swizzle (row&7 == col&7)
  const int NT = Kd >> 6;
  constexpr int AS = 128 * MH;           // A slot size in rows

  float4v acc[4 * MH][4] = {};

  // prologue: tiles 0 and 1, A and B
  stage_half(A, Kd, m0, 0, &As[0][0], t);
  if constexpr (MH == 2) stage_half(A, Kd, m0 + 128, 0, &As[128][0], t);
  stage_half(Bm, Bld, n0, 0, &Bs[0][0], t);
  stage_half(Bm, Bld, n0 + 128, 0, &Bs[128][0], t);
  if (NT > 1) {
    stage_half(A, Kd, m0, 64, &As[AS][0], t);
    if constexpr (MH == 2) stage_half(A, Kd, m0 + 128, 64, &As[AS + 128][0], t);
    stage_half(Bm, Bld, n0, 64, &Bs[256][0], t);
    stage_half(Bm, Bld, n0 + 128, 64, &Bs[384][0], t);
    if constexpr (MH == 2)
      asm volatile("s_waitcnt vmcnt(8)" ::: "memory");  // tile0's 8 loads done
    else
      asm volatile("s_waitcnt vmcnt(6)" ::: "memory");  // tile0's 6 loads done
  } else {
    asm volatile("s_waitcnt vmcnt(0)" ::: "memory");
  }
  __builtin_amdgcn_s_barrier();

  int ar = 0;       // A read slot row-offset (slot k%3)
  int aw = 2 * AS;  // A stage slot row-offset (slot (k+2)%3)
  int br = 0;       // B read offset: 0,256 (parity k&1); stage target = br

  for (int k = 0; k < NT; ++k) {
    short8 a[4][2], b0[2][2], b1[2][2];

    if constexpr (MH == 2) {
      // ---------------- P1 ----------------
#pragma unroll
      for (int i = 0; i < 4; ++i)
#pragma unroll
        for (int s = 0; s < 2; ++s)
          a[i][s] = *(const short8*)&As[ar + wm + i * 16 + col][(((s * 4 + quad) ^ sw)) * 8];
#pragma unroll
      for (int j = 0; j < 2; ++j)
#pragma unroll
        for (int s = 0; s < 2; ++s)
          b0[j][s] = *(const short8*)&Bs[br + wn + j * 16 + col][(((s * 4 + quad) ^ sw)) * 8];
      if (k + 2 < NT) stage_half(A, Kd, m0, (k + 2) * 64, &As[aw][0], t);
      __builtin_amdgcn_s_barrier();
      __builtin_amdgcn_s_setprio(1);
#pragma unroll
      for (int i = 0; i < 4; ++i)
#pragma unroll
        for (int j = 0; j < 2; ++j)
#pragma unroll
          for (int s = 0; s < 2; ++s)
            acc[i][j] = __builtin_amdgcn_mfma_f32_16x16x32_bf16(a[i][s], b0[j][s], acc[i][j], 0, 0, 0);
      __builtin_amdgcn_s_setprio(0);

      // ---------------- P2 ----------------
#pragma unroll
      for (int j = 0; j < 2; ++j)
#pragma unroll
        for (int s = 0; s < 2; ++s)
          b1[j][s] = *(const short8*)&Bs[br + wn + (j + 2) * 16 + col][(((s * 4 + quad) ^ sw)) * 8];
      if (k + 2 < NT) stage_half(A, Kd, m0 + 128, (k + 2) * 64, &As[aw + 128][0], t);
      __builtin_amdgcn_s_barrier();
      __builtin_amdgcn_s_setprio(1);
#pragma unroll
      for (int i = 0; i < 4; ++i)
#pragma unroll
        for (int j = 0; j < 2; ++j)
#pragma unroll
          for (int s = 0; s < 2; ++s)
            acc[i][j + 2] = __builtin_amdgcn_mfma_f32_16x16x32_bf16(a[i][s], b1[j][s], acc[i][j + 2], 0, 0, 0);
      __builtin_amdgcn_s_setprio(0);

      // ---------------- P3 ----------------
#pragma unroll
      for (int i = 0; i < 4; ++i)
#pragma unroll
        for (int s = 0; s < 2; ++s)
          a[i][s] = *(const short8*)&As[ar + wm + (i + 4) * 16 + col][(((s * 4 + quad) ^ sw)) * 8];
      if (k + 2 < NT) stage_half(Bm, Bld, n0, (k + 2) * 64, &Bs[br][0], t);
      __builtin_amdgcn_s_barrier();
      __builtin_amdgcn_s_setprio(1);
#pragma unroll
      for (int i = 0; i < 4; ++i)
#pragma unroll
        for (int j = 0; j < 2; ++j)
#pragma unroll
          for (int s = 0; s < 2; ++s)
            acc[i + 4][j + 2] = __builtin_amdgcn_mfma_f32_16x16x32_bf16(a[i][s], b1[j][s], acc[i + 4][j + 2], 0, 0, 0);
      __builtin_amdgcn_s_setprio(0);

      // ---------------- P4 ----------------
      if (k + 2 < NT) stage_half(Bm, Bld, n0 + 128, (k + 2) * 64, &Bs[br + 128][0], t);
      if (k + 2 < NT) {
        asm volatile("s_waitcnt vmcnt(8)" ::: "memory");   // A(k+1)+B(k+1) landed
      } else if (k + 1 < NT) {
        asm volatile("s_waitcnt vmcnt(0)" ::: "memory");   // drain the last tile
      }
      __builtin_amdgcn_s_barrier();
      __builtin_amdgcn_s_setprio(1);
#pragma unroll
      for (int i = 0; i < 4; ++i)
#pragma unroll
        for (int j = 0; j < 2; ++j)
#pragma unroll
          for (int s = 0; s < 2; ++s)
            acc[i + 4][j] = __builtin_amdgcn_mfma_f32_16x16x32_bf16(a[i][s], b0[j][s], acc[i + 4][j], 0, 0, 0);
      __builtin_amdgcn_s_setprio(0);
    } else {
      // ================ MH == 1 (R12 form): 2 phases ================
      // ---------------- P1 ----------------
#pragma unroll
      for (int i = 0; i < 4; ++i)
#pragma unroll
        for (int s = 0; s < 2; ++s)
          a[i][s] = *(const short8*)&As[ar + wm + i * 16 + col][(((s * 4 + quad) ^ sw)) * 8];
#pragma unroll
      for (int j = 0; j < 2; ++j)
#pragma unroll
        for (int s = 0; s < 2; ++s)
          b0[j][s] = *(const short8*)&Bs[br + wn + j * 16 + col][(((s * 4 + quad) ^ sw)) * 8];
      if (k + 2 < NT) stage_half(A, Kd, m0, (k + 2) * 64, &As[aw][0], t);
      __builtin_amdgcn_s_barrier();
      __builtin_amdgcn_s_setprio(1);
#pragma unroll
      for (int i = 0; i < 4; ++i)
#pragma unroll
        for (int j = 0; j < 2; ++j)
#pragma unroll
          for (int s = 0; s < 2; ++s)
            acc[i][j] = __builtin_amdgcn_mfma_f32_16x16x32_bf16(a[i][s], b0[j][s], acc[i][j], 0, 0, 0);
      __builtin_amdgcn_s_setprio(0);

      // ---------------- P2 ----------------
#pragma unroll
      for (int j = 0; j < 2; ++j)
#pragma unroll
        for (int s = 0; s < 2; ++s)
          b1[j][s] = *(const short8*)&Bs[br + wn + (j + 2) * 16 + col][(((s * 4 + quad) ^ sw)) * 8];
      if (k + 2 < NT) {
        stage_half(Bm, Bld, n0, (k + 2) * 64, &Bs[br][0], t);
        stage_half(Bm, Bld, n0 + 128, (k + 2) * 64, &Bs[br + 128][0], t);
        asm volatile("s_waitcnt vmcnt(6)" ::: "memory");   // A(k+1)+B(k+1) landed
      } else if (k + 1 < NT) {
        asm volatile("s_waitcnt vmcnt(0)" ::: "memory");   // drain the last tile
      }
      __builtin_amdgcn_s_barrier();
      __builtin_amdgcn_s_setprio(1);
#pragma unroll
      for (int i = 0; i < 4; ++i)
#pragma unroll
        for (int j = 0; j < 2; ++j)
#pragma unroll
          for (int s = 0; s < 2; ++s)
            acc[i][j + 2] = __builtin_amdgcn_mfma_f32_16x16x32_bf16(a[i][s], b1[j][s], acc[i][j + 2], 0, 0, 0);
      __builtin_amdgcn_s_setprio(0);
    }

    ar = (ar == 2 * AS) ? 0 : ar + AS;
    aw = (aw == 2 * AS) ? 0 : aw + AS;
    br ^= 256;
  }

  // EPI 2: combine the 32 rowsum partials once per block (Bs is free now).
  float* invb = (float*)&Bs[0][0];
  if (EPI == 2) {
    __syncthreads();   // all waves past their last LDS reads before reuse
    if (t < 128 * MH) {
      float s = 0.f;
#pragma unroll
      for (int p = 0; p < 32; ++p) s += aux[p * 8192 + m0 + t];
      invb[t] = __builtin_amdgcn_rcpf(s);
    }
    __syncthreads();
  }

  // C/D layout: col = lane&15, row = quad*4 + reg  (m89-verified)
  const float LOG2E = 1.44269504f;
  const float c1 = scale * LOG2E;
#pragma unroll
  for (int i = 0; i < 4 * MH; ++i) {
    float invv[4], addm[4], rsum4[4] = {0.f, 0.f, 0.f, 0.f};
    if (EPI == 2) {
#pragma unroll
      for (int r = 0; r < 4; ++r) invv[r] = invb[wm + i * 16 + quad * 4 + r];
    }
    if (EPI == 3) {
#pragma unroll
      for (int r = 0; r < 4; ++r) addm[r] = aux[m0 + wm + i * 16 + quad * 4 + r];
    }
#pragma unroll
    for (int j = 0; j < 4; ++j) {
      const int n = n0 + wn + j * 16 + col;
      float addn = 0.f;
      if (EPI == 0) addn = aux[n];
#pragma unroll
      for (int r = 0; r < 4; ++r) {
        const int m = m0 + wm + i * 16 + quad * 4 + r;
        float v = acc[i][j][r];
        if (EPI == 0) {
          ((short*)C)[(long)m * N + n] = f2bf(v + addn);
        } else if (EPI == 1) {
          float mv = aux[(long)m * N + n];
          float e = exp2f(fmaf(v, c1, mv * LOG2E));  // exp(v*scale+mask); |s|~3, safe
          short q = f2bf(e);
          ((short*)C)[(long)m * N + n] = q;
          rsum4[r] += bf2f(q);  // sum exactly what PV will read
        } else if (EPI == 2) {
          ((float*)C)[(long)m * N + n] = v * invv[r];
        } else {
          ((short*)C)[(long)m * N + n] = f2bf(v + addm[r]);
        }
      }
    }
    if (EPI == 1) {
      // reduce across the 16 lanes of this quad-group; one slot per wave-n-quarter
#pragma unroll
      for (int r = 0; r < 4; ++r) {
        float s = rsum4[r];
        s += __shfl_xor(s, 1);
        s += __shfl_xor(s, 2);
        s += __shfl_xor(s, 4);
        s += __shfl_xor(s, 8);
        if (col == 0)
          rsum[(wave & 3) * 8192 + m0 + wm + i * 16 + quad * 4 + r] = s;
      }
    }
  }
}

// ================= fused cooperative kernel: prep -> qkv -> scores -> pv =====
__global__ __launch_bounds__(512, 2) void fused_kernel(
    const float* __restrict__ x, const float* __restrict__ mask,
    const float* __restrict__ wq, const float* __restrict__ bq,
    const float* __restrict__ wk, const float* __restrict__ bk,
    const float* __restrict__ wv, const float* __restrict__ bv,
    float* __restrict__ out, char* ws) {
  __shared__ alignas(16) short As[768][64];   // 96 KB
  __shared__ alignas(16) short Bs[512][64];   // 64 KB (total 160 KB)
  const size_t MB = 1048576;
  short* x_bf   = (short*)ws;               // 16 MB; dead after qkv
  float* rspart = (float*)ws;               // 1 MB, aliases x_bf (scores->pv)
  short* w_bf   = (short*)(ws + 16 * MB);   // 6 MB
  short* QK     = (short*)(ws + 22 * MB);   // 32 MB
  short* Vt     = (short*)(ws + 54 * MB);   // 16 MB
  short* P      = (short*)(ws + 70 * MB);   // 32 MB
  float* bcat   = (float*)(ws + 70 * MB);   // 8 KB, head of P (dead before P)

  const int bid = blockIdx.x;                    // 256
  const int tid = threadIdx.x;                   // 512
  const unsigned gtid = (unsigned)bid * 512u + (unsigned)tid;

  // ---- phase 0: prep (grid-stride) + queue reset ----
  if (gtid == 0) g_vt_ctr = 0u;
#pragma unroll 1
  for (unsigned i = gtid; i < 786432u; i += 131072u) {    // weights: 6 iters
    const unsigned seg = i >> 18, idx = i & 262143u;
    const float* w = seg == 0 ? wq : (seg == 1 ? wk : wv);
    float4v v = ((const float4v*)w)[idx];
    short4v o;
    o.x = f2bf(v.x); o.y = f2bf(v.y); o.z = f2bf(v.z); o.w = f2bf(v.w);
    ((short4v*)(w_bf + (long)seg * 1048576))[idx] = o;
  }
#pragma unroll 1
  for (unsigned i = gtid; i < 2097152u; i += 131072u) {   // x: 16 iters
    float4v v = ((const float4v*)x)[i];
    short4v o;
    o.x = f2bf(v.x); o.y = f2bf(v.y); o.z = f2bf(v.z); o.w = f2bf(v.w);
    ((short4v*)x_bf)[i] = o;
  }
  if (gtid < 2048u) bcat[gtid] = gtid < 1024u ? bq[gtid] : bk[gtid - 1024u];
  __threadfence();
  cg::this_grid().sync();

  const int g = (bid & 7) * 32 + (bid >> 3);     // bijective XCD swizzle

  // ---- phase 1: qkv. Static QK tile (interleaved Q/K share x panel), then
  //      dynamic Vt tiles from the global queue (128 tiles, MH=2). ----
  {
    const int pair = g >> 1, bz = g & 1;         // 32 m-tiles x 4 n-tiles
    const int m0 = (pair >> 2) * 256, n0 = (pair & 3) * 256;
    gemm_body<0, 2>(x_bf, w_bf + (long)bz * 1048576, QK + (long)bz * 8388608,
                    bcat + bz * 1024, nullptr, 1.f, 1024, 1024, 1024, m0, n0, As, Bs);
  }
  unsigned* vt_sh = (unsigned*)&As[0][0];        // As is dead between tiles
  for (;;) {
    if (tid == 0) *vt_sh = atomicAdd(&g_vt_ctr, 1u);
    __syncthreads();
    const unsigned v = *vt_sh;
    __syncthreads();                             // all read before As reused
    if (v >= 128u) break;
    const int m0 = (int)(v >> 5) * 256, n0 = (int)(v & 31u) * 256;  // 4m x 32n
    gemm_body<3, 2>(w_bf + 2097152, x_bf, Vt, bv, nullptr, 1.f,
                    8192, 1024, 1024, m0, n0, As, Bs);
  }
  __threadfence();
  cg::this_grid().sync();

  // ---- phase 2: scores (identical mapping to R16) ----
  {
    const int bz = g >> 6, t2 = g & 63;          // 8 m-tiles x 8 n-tiles
    const int m0 = (t2 >> 3) * 256, n0 = (t2 & 7) * 256;
    gemm_body<1, 2>(QK + (long)bz * 2097152, QK + 8388608 + (long)bz * 2097152,
                    P + (long)bz * 4194304, mask,
                    rspart + (long)(n0 >> 8) * 4 * 8192 + bz * 2048, 0.03125f,
                    2048, 1024, 1024, m0, n0, As, Bs);
  }
  __threadfence();
  cg::this_grid().sync();

  // ---- phase 3: pv (identical mapping to R16) ----
  {
    const int bz = g >> 6, t2 = g & 63;          // 16 m-tiles x 4 n-tiles
    const int m0 = (t2 >> 2) * 128, n0 = (t2 & 3) * 256;
    gemm_body<2, 1>(P + (long)bz * 4194304, Vt + (long)bz * 2048,
                    out + (long)bz * 2097152, rspart + bz * 2048, nullptr, 1.f,
                    1024, 2048, 8192, m0, n0, As, Bs);
  }
}

// ================= R16 fallback path (used only if coop launch errors) ======
__global__ __launch_bounds__(256) void prep_kernel(const float* __restrict__ x,
                                                   const float* __restrict__ wq,
                                                   const float* __restrict__ wk,
                                                   const float* __restrict__ wv,
                                                   const float* __restrict__ bq,
                                                   const float* __restrict__ bk,
                                                   short* __restrict__ x_bf,
                                                   short* __restrict__ w_bf,
                                                   float* __restrict__ bcat) {
  int b = blockIdx.x;
  if (b < 3072) {
    int seg = b >> 10;
    const float* w = seg == 0 ? wq : (seg == 1 ? wk : wv);
    int i = (b - (seg << 10)) * 256 + threadIdx.x;
    float4v v = ((const float4v*)w)[i];
    short4v o;
    o.x = f2bf(v.x); o.y = f2bf(v.y); o.z = f2bf(v.z); o.w = f2bf(v.w);
    ((short4v*)(w_bf + (long)seg * 1048576))[i] = o;
  } else if (b < 11264) {
    int i = (b - 3072) * 256 + threadIdx.x;
    float4v v = ((const float4v*)x)[i];
    short4v o;
    o.x = f2bf(v.x); o.y = f2bf(v.y); o.z = f2bf(v.z); o.w = f2bf(v.w);
    ((short4v*)x_bf)[i] = o;
  } else {
    int i = (b - 11264) * 256 + threadIdx.x;
    if (i < 2048) bcat[i] = i < 1024 ? bq[i] : bk[i - 1024];
  }
}

__global__ __launch_bounds__(512, 2) void qkv_kernel(const short* __restrict__ x_bf,
                                                     const short* __restrict__ w_bf,
                                                     short* __restrict__ QK,
                                                     short* __restrict__ Vt,
                                                     const float* __restrict__ bcat,
                                                     const float* __restrict__ bv) {
  __shared__ alignas(16) short As[768][64];
  __shared__ alignas(16) short Bs[512][64];
  const int b = blockIdx.x;                   // 384
  const int g = (b & 7) * 48 + (b >> 3);
  if (g < 256) {
    const int pair = g >> 1, bz = g & 1;
    const int m0 = (pair >> 2) * 256, n0 = (pair & 3) * 256;
    gemm_body<0, 2>(x_bf, w_bf + (long)bz * 1048576, QK + (long)bz * 8388608,
                    bcat + bz * 1024, nullptr, 1.f, 1024, 1024, 1024, m0, n0, As, Bs);
  } else {
    const int v = g - 256;
    const int m0 = (v >> 5) * 256, n0 = (v & 31) * 256;
    gemm_body<3, 2>(w_bf + 2097152, x_bf, Vt, bv, nullptr, 1.f,
                    8192, 1024, 1024, m0, n0, As, Bs);
  }
}

__global__ __launch_bounds__(512, 2) void scores_kernel(const short* __restrict__ Q,
                                                        const short* __restrict__ Kb,
                                                        short* __restrict__ P,
                                                        const float* __restrict__ mask,
                                                        float* __restrict__ rspart) {
  __shared__ alignas(16) short As[768][64];
  __shared__ alignas(16) short Bs[512][64];
  const int b = blockIdx.x;                  // 256
  const int g = (b & 7) * 32 + (b >> 3);
  const int bz = g >> 6, t2 = g & 63;
  const int m0 = (t2 >> 3) * 256, n0 = (t2 & 7) * 256;
  gemm_body<1, 2>(Q + (long)bz * 2097152, Kb + (long)bz * 2097152,
                  P + (long)bz * 4194304, mask,
                  rspart + (long)(n0 >> 8) * 4 * 8192 + bz * 2048, 0.03125f,
                  2048, 1024, 1024, m0, n0, As, Bs);
}

__global__ __launch_bounds__(512, 2) void pv_kernel(const short* __restrict__ P,
                                                    const short* __restrict__ Vt,
                                                    float* __restrict__ out,
                                                    const float* __restrict__ rspart) {
  __shared__ alignas(16) short As[384][64];
  __shared__ alignas(16) short Bs[512][64];
  const int b = blockIdx.x;                 // 256
  const int g = (b & 7) * 32 + (b >> 3);
  const int bz = g >> 6, t2 = g & 63;
  const int m0 = (t2 >> 2) * 128, n0 = (t2 & 3) * 256;
  gemm_body<2, 1>(P + (long)bz * 4194304, Vt + (long)bz * 2048,
                  out + (long)bz * 2097152, rspart + bz * 2048, nullptr, 1.f,
                  1024, 2048, 8192, m0, n0, As, Bs);
}

extern "C" void kernel_launch(void* const* d_in, const int* in_sizes, int n_in,
                              void* d_out, int out_size, void* d_ws, size_t ws_size,
                              hipStream_t stream) {
  const float* x    = (const float*)d_in[0];
  const float* mask = (const float*)d_in[1];
  const float* wq   = (const float*)d_in[2];
  const float* bq   = (const float*)d_in[3];
  const float* wk   = (const float*)d_in[4];
  const float* bk   = (const float*)d_in[5];
  const float* wv   = (const float*)d_in[6];
  const float* bv   = (const float*)d_in[7];
  float* out = (float*)d_out;
  char* ws = (char*)d_ws;

  void* kargs[] = {(void*)&x, (void*)&mask, (void*)&wq, (void*)&bq, (void*)&wk,
                   (void*)&bk, (void*)&wv, (void*)&bv, (void*)&out, (void*)&ws};
  hipError_t err = hipLaunchCooperativeKernel((void*)fused_kernel, dim3(256),
                                              dim3(512), kargs, 0, stream);
  if (err != hipSuccess) {
    // R16 4-dispatch fallback
    const size_t MB = 1024 * 1024;
    short* x_bf   = (short*)(ws);
    float* rspart = (float*)(ws);
    short* w_bf   = (short*)(ws + 16 * MB);
    short* QK     = (short*)(ws + 22 * MB);
    short* Vt     = (short*)(ws + 54 * MB);
    short* P      = (short*)(ws + 70 * MB);
    float* bcat   = (float*)(ws + 70 * MB);
    prep_kernel<<<11272, 256, 0, stream>>>(x, wq, wk, wv, bq, bk, x_bf, w_bf, bcat);
    qkv_kernel<<<384, 512, 0, stream>>>(x_bf, w_bf, QK, Vt, bcat, bv);
    short* Q  = QK;
    short* Kb = QK + 8388608;
    scores_kernel<<<256, 512, 0, stream>>>(Q, Kb, P, mask, rspart);
    pv_kernel<<<256, 512, 0, stream>>>(P, Vt, out, rspart);
  }
}

// Round 10
// 256.796 us; speedup vs baseline: 2.1158x; 2.1158x over previous
//
#include <hip/hip_runtime.h>

// SimpleSelfAttention: B=4, S=2048, D=1024, fp32 in/out, bf16 MFMA internally.
// R18 = exact revert to R16 (measured session-best 254.0us). R17's cooperative
//       fusion FAILED hard (fused kernel 445us: grid.sync() convoying kills
//       the cross-dispatch tail/head overlap the HW dispatcher gives for free,
//       and 131072 spinning threads at 3 grid syncs burn L2/HBM bandwidth
//       against the stragglers -- MfmaUtil 11%, FETCH +100MB).
//   qkv: R13 256^2 MH=2 body, 384 blocks, Q/K tile interleave (bz=g&1).
//   scores: 256^2 MH=2, 256 blocks.
//   pv: R12-form 128x256 MH=1, 256 blocks, full machine round.

typedef __attribute__((ext_vector_type(8))) short short8;
typedef __attribute__((ext_vector_type(4))) short short4v;
typedef __attribute__((ext_vector_type(4))) float float4v;

__device__ __forceinline__ short f2bf(float f) {
  unsigned u = __builtin_bit_cast(unsigned, f);
  u += 0x7fffu + ((u >> 16) & 1u);  // RNE; inputs finite
  return (short)(u >> 16);
}
__device__ __forceinline__ float bf2f(short s) {
  unsigned u = ((unsigned)(unsigned short)s) << 16;
  return __builtin_bit_cast(float, u);
}

// async global->LDS, 16B per lane. LDS dest = wave-uniform base + lane*16.
__device__ __forceinline__ void gl2lds16(const void* g, void* l) {
  __builtin_amdgcn_global_load_lds((const __attribute__((address_space(1))) void*)g,
                                   (__attribute__((address_space(3))) void*)l, 16, 0, 0);
}

// ---------- merged prep: w cvt (3x1024^2) + x cvt (8192x1024) + bias concat ----------
__global__ __launch_bounds__(256) void prep_kernel(const float* __restrict__ x,
                                                   const float* __restrict__ wq,
                                                   const float* __restrict__ wk,
                                                   const float* __restrict__ wv,
                                                   const float* __restrict__ bq,
                                                   const float* __restrict__ bk,
                                                   short* __restrict__ x_bf,
                                                   short* __restrict__ w_bf,
                                                   float* __restrict__ bcat) {
  int b = blockIdx.x;
  if (b < 3072) {                      // weights
    int seg = b >> 10;                 // 0,1,2 (wave-uniform)
    const float* w = seg == 0 ? wq : (seg == 1 ? wk : wv);
    int i = (b - (seg << 10)) * 256 + threadIdx.x;
    float4v v = ((const float4v*)w)[i];
    short4v o;
    o.x = f2bf(v.x); o.y = f2bf(v.y); o.z = f2bf(v.z); o.w = f2bf(v.w);
    ((short4v*)(w_bf + (long)seg * 1048576))[i] = o;
  } else if (b < 11264) {              // x
    int i = (b - 3072) * 256 + threadIdx.x;  // < 2097152
    float4v v = ((const float4v*)x)[i];
    short4v o;
    o.x = f2bf(v.x); o.y = f2bf(v.y); o.z = f2bf(v.z); o.w = f2bf(v.w);
    ((short4v*)x_bf)[i] = o;
  } else {                             // Q,K biases (bv handled by Vt gemm)
    int i = (b - 11264) * 256 + threadIdx.x;
    if (i < 2048) bcat[i] = i < 1024 ? bq[i] : bk[i - 1024];
  }
}

// ---------- staging: one 128x64 bf16 half-tile, 2 x global_load_lds per thread ----
// LDS layout per row r (128 B): 16B chunk slot s holds global chunk s ^ (r&7).
__device__ __forceinline__ void stage_half(const short* __restrict__ g, int ld,
                                           int grow0, int kt, short* lds, int t) {
  const int r = t >> 3;                         // 0..63
  const int cch = (t & 7) ^ (r & 7);            // global chunk for this slot
  const long co = (long)kt + cch * 8;
  gl2lds16(g + (long)(grow0 + r) * ld + co, lds + t * 8);
  gl2lds16(g + (long)(grow0 + 64 + r) * ld + co, lds + 4096 + t * 8);
}

// ---------- shared GEMM body: C[m,n] = sum_k A[m,k]*B[n,k], BK=64 ----
// MH = number of 128-row A halves. Tile = (128*MH) x 256. 512 threads.
// 8 waves: wm = (wave>>2)*64*MH rows, wn = (wave&3)*64 cols per wave.
// MH=2 (R11/R13-proven, 66us): A 3 slots (rot mod 3), B 2 slots (parity).
//   4 phases, one barrier each; A(k+2) staged P1/P2 (dead slot), B(k+2)
//   staged P3/P4 into live-parity slot (all B reads lgkm-complete before
//   P3's barrier); vmcnt(8) end-P4 drains A(k+1)+B(k+1).
// MH=1 (R12-proven): A 3 slots, B 2 slots. 2 phases:
//   P1: read a+b0 [12]; stage A(k+2); bar; MFMA j0-1
//   P2: read b1 [4]; stage Blo+Bhi(k+2) into live parity; vmcnt(6); bar; MFMA
// EPI 0: +aux[n], store bf16.
// EPI 1: store bf16 exp(v*scale + aux[m*N+n]); partial row sums ->
//        rsum[(wave&3)*8192 + m] (32 slots per (batch,row) total).
// EPI 2: rowsums = sum of 32 partials aux[p*8192+m]; store fp32 v * rcp(rowsum).
// EPI 3: +aux[m], store bf16.
// All pointers pre-offset per batch by the caller.
template <int EPI, int MH>
__device__ __forceinline__ void gemm_body(const short* __restrict__ A,
                                          const short* __restrict__ Bm,
                                          void* __restrict__ C,
                                          const float* __restrict__ aux,
                                          float* __restrict__ rsum, float scale,
                                          int N, int Kd, int Bld, int m0, int n0,
                                          short (*As)[64], short (*Bs)[64]) {
  const int t = threadIdx.x;
  const int lane = t & 63;
  const int wave = t >> 6;               // 0..7
  const int wm = (wave >> 2) * 64 * MH;  // MH=2: 0/128; MH=1: 0/64
  const int wn = (wave & 3) * 64;        // 0,64,128,192
  const int col = lane & 15, quad = lane >> 4;
  const int sw = col & 7;                // reader swizzle (row&7 == col&7)
  const int NT = Kd >> 6;
  constexpr int AS = 128 * MH;           // A slot size in rows

  float4v acc[4 * MH][4] = {};

  // prologue: tiles 0 and 1, A and B
  stage_half(A, Kd, m0, 0, &As[0][0], t);
  if constexpr (MH == 2) stage_half(A, Kd, m0 + 128, 0, &As[128][0], t);
  stage_half(Bm, Bld, n0, 0, &Bs[0][0], t);
  stage_half(Bm, Bld, n0 + 128, 0, &Bs[128][0], t);
  if (NT > 1) {
    stage_half(A, Kd, m0, 64, &As[AS][0], t);
    if constexpr (MH == 2) stage_half(A, Kd, m0 + 128, 64, &As[AS + 128][0], t);
    stage_half(Bm, Bld, n0, 64, &Bs[256][0], t);
    stage_half(Bm, Bld, n0 + 128, 64, &Bs[384][0], t);
    if constexpr (MH == 2)
      asm volatile("s_waitcnt vmcnt(8)" ::: "memory");  // tile0's 8 loads done
    else
      asm volatile("s_waitcnt vmcnt(6)" ::: "memory");  // tile0's 6 loads done
  } else {
    asm volatile("s_waitcnt vmcnt(0)" ::: "memory");
  }
  __builtin_amdgcn_s_barrier();

  int ar = 0;       // A read slot row-offset (slot k%3)
  int aw = 2 * AS;  // A stage slot row-offset (slot (k+2)%3)
  int br = 0;       // B read offset: 0,256 (parity k&1); stage target = br

  for (int k = 0; k < NT; ++k) {
    short8 a[4][2], b0[2][2], b1[2][2];

    if constexpr (MH == 2) {
      // ---------------- P1 ----------------
#pragma unroll
      for (int i = 0; i < 4; ++i)
#pragma unroll
        for (int s = 0; s < 2; ++s)
          a[i][s] = *(const short8*)&As[ar + wm + i * 16 + col][(((s * 4 + quad) ^ sw)) * 8];
#pragma unroll
      for (int j = 0; j < 2; ++j)
#pragma unroll
        for (int s = 0; s < 2; ++s)
          b0[j][s] = *(const short8*)&Bs[br + wn + j * 16 + col][(((s * 4 + quad) ^ sw)) * 8];
      if (k + 2 < NT) stage_half(A, Kd, m0, (k + 2) * 64, &As[aw][0], t);
      __builtin_amdgcn_s_barrier();
      __builtin_amdgcn_s_setprio(1);
#pragma unroll
      for (int i = 0; i < 4; ++i)
#pragma unroll
        for (int j = 0; j < 2; ++j)
#pragma unroll
          for (int s = 0; s < 2; ++s)
            acc[i][j] = __builtin_amdgcn_mfma_f32_16x16x32_bf16(a[i][s], b0[j][s], acc[i][j], 0, 0, 0);
      __builtin_amdgcn_s_setprio(0);

      // ---------------- P2 ----------------
#pragma unroll
      for (int j = 0; j < 2; ++j)
#pragma unroll
        for (int s = 0; s < 2; ++s)
          b1[j][s] = *(const short8*)&Bs[br + wn + (j + 2) * 16 + col][(((s * 4 + quad) ^ sw)) * 8];
      if (k + 2 < NT) stage_half(A, Kd, m0 + 128, (k + 2) * 64, &As[aw + 128][0], t);
      __builtin_amdgcn_s_barrier();
      __builtin_amdgcn_s_setprio(1);
#pragma unroll
      for (int i = 0; i < 4; ++i)
#pragma unroll
        for (int j = 0; j < 2; ++j)
#pragma unroll
          for (int s = 0; s < 2; ++s)
            acc[i][j + 2] = __builtin_amdgcn_mfma_f32_16x16x32_bf16(a[i][s], b1[j][s], acc[i][j + 2], 0, 0, 0);
      __builtin_amdgcn_s_setprio(0);

      // ---------------- P3 ----------------
#pragma unroll
      for (int i = 0; i < 4; ++i)
#pragma unroll
        for (int s = 0; s < 2; ++s)
          a[i][s] = *(const short8*)&As[ar + wm + (i + 4) * 16 + col][(((s * 4 + quad) ^ sw)) * 8];
      if (k + 2 < NT) stage_half(Bm, Bld, n0, (k + 2) * 64, &Bs[br][0], t);
      __builtin_amdgcn_s_barrier();
      __builtin_amdgcn_s_setprio(1);
#pragma unroll
      for (int i = 0; i < 4; ++i)
#pragma unroll
        for (int j = 0; j < 2; ++j)
#pragma unroll
          for (int s = 0; s < 2; ++s)
            acc[i + 4][j + 2] = __builtin_amdgcn_mfma_f32_16x16x32_bf16(a[i][s], b1[j][s], acc[i + 4][j + 2], 0, 0, 0);
      __builtin_amdgcn_s_setprio(0);

      // ---------------- P4 ----------------
      if (k + 2 < NT) stage_half(Bm, Bld, n0 + 128, (k + 2) * 64, &Bs[br + 128][0], t);
      if (k + 2 < NT) {
        asm volatile("s_waitcnt vmcnt(8)" ::: "memory");   // A(k+1)+B(k+1) landed
      } else if (k + 1 < NT) {
        asm volatile("s_waitcnt vmcnt(0)" ::: "memory");   // drain the last tile
      }
      __builtin_amdgcn_s_barrier();
      __builtin_amdgcn_s_setprio(1);
#pragma unroll
      for (int i = 0; i < 4; ++i)
#pragma unroll
        for (int j = 0; j < 2; ++j)
#pragma unroll
          for (int s = 0; s < 2; ++s)
            acc[i + 4][j] = __builtin_amdgcn_mfma_f32_16x16x32_bf16(a[i][s], b0[j][s], acc[i + 4][j], 0, 0, 0);
      __builtin_amdgcn_s_setprio(0);
    } else {
      // ================ MH == 1 (R12 form): 2 phases ================
      // ---------------- P1 ----------------
#pragma unroll
      for (int i = 0; i < 4; ++i)
#pragma unroll
        for (int s = 0; s < 2; ++s)
          a[i][s] = *(const short8*)&As[ar + wm + i * 16 + col][(((s * 4 + quad) ^ sw)) * 8];
#pragma unroll
      for (int j = 0; j < 2; ++j)
#pragma unroll
        for (int s = 0; s < 2; ++s)
          b0[j][s] = *(const short8*)&Bs[br + wn + j * 16 + col][(((s * 4 + quad) ^ sw)) * 8];
      if (k + 2 < NT) stage_half(A, Kd, m0, (k + 2) * 64, &As[aw][0], t);
      __builtin_amdgcn_s_barrier();
      __builtin_amdgcn_s_setprio(1);
#pragma unroll
      for (int i = 0; i < 4; ++i)
#pragma unroll
        for (int j = 0; j < 2; ++j)
#pragma unroll
          for (int s = 0; s < 2; ++s)
            acc[i][j] = __builtin_amdgcn_mfma_f32_16x16x32_bf16(a[i][s], b0[j][s], acc[i][j], 0, 0, 0);
      __builtin_amdgcn_s_setprio(0);

      // ---------------- P2 ----------------
#pragma unroll
      for (int j = 0; j < 2; ++j)
#pragma unroll
        for (int s = 0; s < 2; ++s)
          b1[j][s] = *(const short8*)&Bs[br + wn + (j + 2) * 16 + col][(((s * 4 + quad) ^ sw)) * 8];
      if (k + 2 < NT) {
        stage_half(Bm, Bld, n0, (k + 2) * 64, &Bs[br][0], t);
        stage_half(Bm, Bld, n0 + 128, (k + 2) * 64, &Bs[br + 128][0], t);
        asm volatile("s_waitcnt vmcnt(6)" ::: "memory");   // A(k+1)+B(k+1) landed
      } else if (k + 1 < NT) {
        asm volatile("s_waitcnt vmcnt(0)" ::: "memory");   // drain the last tile
      }
      __builtin_amdgcn_s_barrier();
      __builtin_amdgcn_s_setprio(1);
#pragma unroll
      for (int i = 0; i < 4; ++i)
#pragma unroll
        for (int j = 0; j < 2; ++j)
#pragma unroll
          for (int s = 0; s < 2; ++s)
            acc[i][j + 2] = __builtin_amdgcn_mfma_f32_16x16x32_bf16(a[i][s], b1[j][s], acc[i][j + 2], 0, 0, 0);
      __builtin_amdgcn_s_setprio(0);
    }

    ar = (ar == 2 * AS) ? 0 : ar + AS;
    aw = (aw == 2 * AS) ? 0 : aw + AS;
    br ^= 256;
  }

  // EPI 2: combine the 32 rowsum partials once per block (Bs is free now).
  float* invb = (float*)&Bs[0][0];
  if (EPI == 2) {
    __syncthreads();   // all waves past their last LDS reads before reuse
    if (t < 128 * MH) {
      float s = 0.f;
#pragma unroll
      for (int p = 0; p < 32; ++p) s += aux[p * 8192 + m0 + t];
      invb[t] = __builtin_amdgcn_rcpf(s);
    }
    __syncthreads();
  }

  // C/D layout: col = lane&15, row = quad*4 + reg  (m89-verified)
  const float LOG2E = 1.44269504f;
  const float c1 = scale * LOG2E;
#pragma unroll
  for (int i = 0; i < 4 * MH; ++i) {
    float invv[4], addm[4], rsum4[4] = {0.f, 0.f, 0.f, 0.f};
    if (EPI == 2) {
#pragma unroll
      for (int r = 0; r < 4; ++r) invv[r] = invb[wm + i * 16 + quad * 4 + r];
    }
    if (EPI == 3) {
#pragma unroll
      for (int r = 0; r < 4; ++r) addm[r] = aux[m0 + wm + i * 16 + quad * 4 + r];
    }
#pragma unroll
    for (int j = 0; j < 4; ++j) {
      const int n = n0 + wn + j * 16 + col;
      float addn = 0.f;
      if (EPI == 0) addn = aux[n];
#pragma unroll
      for (int r = 0; r < 4; ++r) {
        const int m = m0 + wm + i * 16 + quad * 4 + r;
        float v = acc[i][j][r];
        if (EPI == 0) {
          ((short*)C)[(long)m * N + n] = f2bf(v + addn);
        } else if (EPI == 1) {
          float mv = aux[(long)m * N + n];
          float e = exp2f(fmaf(v, c1, mv * LOG2E));  // exp(v*scale+mask); |s|~3, safe
          short q = f2bf(e);
          ((short*)C)[(long)m * N + n] = q;
          rsum4[r] += bf2f(q);  // sum exactly what PV will read
        } else if (EPI == 2) {
          ((float*)C)[(long)m * N + n] = v * invv[r];
        } else {
          ((short*)C)[(long)m * N + n] = f2bf(v + addm[r]);
        }
      }
    }
    if (EPI == 1) {
      // reduce across the 16 lanes of this quad-group; one slot per wave-n-quarter
#pragma unroll
      for (int r = 0; r < 4; ++r) {
        float s = rsum4[r];
        s += __shfl_xor(s, 1);
        s += __shfl_xor(s, 2);
        s += __shfl_xor(s, 4);
        s += __shfl_xor(s, 8);
        if (col == 0)
          rsum[(wave & 3) * 8192 + m0 + wm + i * 16 + quad * 4 + r] = s;
      }
    }
  }
}

// ---------- QK interleaved (g<256: bz=g&1 shares x panel) + Vt (g>=256) ----------
__global__ __launch_bounds__(512, 2) void qkv_kernel(const short* __restrict__ x_bf,
                                                     const short* __restrict__ w_bf,
                                                     short* __restrict__ QK,
                                                     short* __restrict__ Vt,
                                                     const float* __restrict__ bcat,
                                                     const float* __restrict__ bv) {
  __shared__ alignas(16) short As[768][64];   // [3 slots][256][64]
  __shared__ alignas(16) short Bs[512][64];   // [2 slots][256][64]
  const int b = blockIdx.x;                   // 384
  const int g = (b & 7) * 48 + (b >> 3);      // bijective (384 % 8 == 0)
  if (g < 256) {
    // Q/K interleave: consecutive same-XCD blocks = (Q,m,n),(K,m,n) -> shared
    // x A-panel in L2.
    const int pair = g >> 1, bz = g & 1;      // 32 m-tiles x 4 n-tiles
    const int m0 = (pair >> 2) * 256, n0 = (pair & 3) * 256;
    gemm_body<0, 2>(x_bf, w_bf + (long)bz * 1048576, QK + (long)bz * 8388608,
                    bcat + bz * 1024, nullptr, 1.f, 1024, 1024, 1024, m0, n0, As, Bs);
  } else {
    const int v = g - 256;                    // 4 m-tiles x 32 n-tiles
    const int m0 = (v >> 5) * 256, n0 = (v & 31) * 256;
    gemm_body<3, 2>(w_bf + 2097152, x_bf, Vt, bv, nullptr, 1.f,
                    8192, 1024, 1024, m0, n0, As, Bs);
  }
}

// ---------- P = exp(Q K^T /32 + mask), partial rowsums -> rspart ----------
__global__ __launch_bounds__(512, 2) void scores_kernel(const short* __restrict__ Q,
                                                        const short* __restrict__ Kb,
                                                        short* __restrict__ P,
                                                        const float* __restrict__ mask,
                                                        float* __restrict__ rspart) {
  __shared__ alignas(16) short As[768][64];
  __shared__ alignas(16) short Bs[512][64];
  const int b = blockIdx.x;                  // 256
  const int g = (b & 7) * 32 + (b >> 3);
  const int bz = g >> 6, t2 = g & 63;        // 8 m-tiles x 8 n-tiles per batch
  const int m0 = (t2 >> 3) * 256, n0 = (t2 & 7) * 256;
  // 4 slots per n-tile (one per wave-n-quarter): 8 n-tiles * 4 = 32 partials/row
  gemm_body<1, 2>(Q + (long)bz * 2097152, Kb + (long)bz * 2097152,
                  P + (long)bz * 4194304, mask,
                  rspart + (long)(n0 >> 8) * 4 * 8192 + bz * 2048, 0.03125f,
                  2048, 1024, 1024, m0, n0, As, Bs);
}

// ---------- out = (P V) / rowsum, 128x256 tiles (R12 form), full round ----------
__global__ __launch_bounds__(512, 2) void pv_kernel(const short* __restrict__ P,
                                                    const short* __restrict__ Vt,
                                                    float* __restrict__ out,
                                                    const float* __restrict__ rspart) {
  __shared__ alignas(16) short As[384][64];   // 3x128 rows (48KB)
  __shared__ alignas(16) short Bs[512][64];   // 2x256 rows (64KB)
  const int b = blockIdx.x;                 // 256
  const int g = (b & 7) * 32 + (b >> 3);
  const int bz = g >> 6, t2 = g & 63;       // 16 m-tiles (128) x 4 n-tiles (256)
  const int m0 = (t2 >> 2) * 128, n0 = (t2 & 3) * 256;
  gemm_body<2, 1>(P + (long)bz * 4194304, Vt + (long)bz * 2048,
                  out + (long)bz * 2097152, rspart + bz * 2048, nullptr, 1.f,
                  1024, 2048, 8192, m0, n0, As, Bs);
}

extern "C" void kernel_launch(void* const* d_in, const int* in_sizes, int n_in,
                              void* d_out, int out_size, void* d_ws, size_t ws_size,
                              hipStream_t stream) {
  const float* x    = (const float*)d_in[0];
  const float* mask = (const float*)d_in[1];
  const float* wq   = (const float*)d_in[2];
  const float* bq   = (const float*)d_in[3];
  const float* wk   = (const float*)d_in[4];
  const float* bk   = (const float*)d_in[5];
  const float* wv   = (const float*)d_in[6];
  const float* bv   = (const float*)d_in[7];
  float* out = (float*)d_out;

  char* ws = (char*)d_ws;
  const size_t MB = 1024 * 1024;
  short* x_bf   = (short*)(ws);             // 16 MB [8192,1024]; dead after qkv
  float* rspart = (float*)(ws);             // 1 MB [32][8192], aliases x_bf
  short* w_bf   = (short*)(ws + 16 * MB);   // 6 MB [3][1024,1024]
  short* QK     = (short*)(ws + 22 * MB);   // 32 MB [2][8192,1024]
  short* Vt     = (short*)(ws + 54 * MB);   // 16 MB [1024][8192] = [d][b*2048+s]
  short* P      = (short*)(ws + 70 * MB);   // 32 MB [4][2048][2048] (unnormalized exp)
  float* bcat   = (float*)(ws + 70 * MB);   // 8 KB, aliases head of P (dead before P)

  prep_kernel<<<11272, 256, 0, stream>>>(x, wq, wk, wv, bq, bk, x_bf, w_bf, bcat);

  // Q,K projections (interleaved) + Vt GEMM, all MH=2, XCD-swizzled
  qkv_kernel<<<384, 512, 0, stream>>>(x_bf, w_bf, QK, Vt, bcat, bv);

  short* Q  = QK;
  short* Kb = QK + 8388608;

  // P = exp(Q K^T / 32 + mask) -> bf16 unnormalized; rspart gets partial sums
  scores_kernel<<<256, 512, 0, stream>>>(Q, Kb, P, mask, rspart);

  // out = (P V) / rowsum, full machine round (R12 measured-best form)
  pv_kernel<<<256, 512, 0, stream>>>(P, Vt, out, rspart);
}

// Round 12
// 249.206 us; speedup vs baseline: 2.1802x; 1.0305x over previous
//
#include <hip/hip_runtime.h>

// SimpleSelfAttention: B=4, S=2048, D=1024, fp32 in/out, bf16 MFMA internally.
// R20 = R19 resubmitted verbatim (Round-11 bench was an infra failure:
//       "MI355X container failed twice" -- no kernel signal). R19 = R18 +
//       grid-strided prep (the only un-measured residual). R18's accounting:
//       total 256.8 - qkv 67 - scores(<67) - pv(<67) leaves prep+boundaries
//       ~60us vs prep's ~12us traffic ideal. Old prep was the G11
//       anti-pattern: 11272 blocks x 1 float4/thread. New prep: 2048 blocks
//       x 256 threads, grid-stride (~5.5 float4s/thread -> MLP).
//       GEMM kernels byte-identical to R18 (qkv R13-body 384blk + Q/K
//       interleave; scores 256^2 MH=2; pv R12-form 128x256 MH=1).

typedef __attribute__((ext_vector_type(8))) short short8;
typedef __attribute__((ext_vector_type(4))) short short4v;
typedef __attribute__((ext_vector_type(4))) float float4v;

__device__ __forceinline__ short f2bf(float f) {
  unsigned u = __builtin_bit_cast(unsigned, f);
  u += 0x7fffu + ((u >> 16) & 1u);  // RNE; inputs finite
  return (short)(u >> 16);
}
__device__ __forceinline__ float bf2f(short s) {
  unsigned u = ((unsigned)(unsigned short)s) << 16;
  return __builtin_bit_cast(float, u);
}

// async global->LDS, 16B per lane. LDS dest = wave-uniform base + lane*16.
__device__ __forceinline__ void gl2lds16(const void* g, void* l) {
  __builtin_amdgcn_global_load_lds((const __attribute__((address_space(1))) void*)g,
                                   (__attribute__((address_space(3))) void*)l, 16, 0, 0);
}

// ---------- grid-strided prep: w cvt (3x1024^2) + x cvt (8192x1024) + biases ----
__global__ __launch_bounds__(256) void prep_kernel(const float* __restrict__ x,
                                                   const float* __restrict__ wq,
                                                   const float* __restrict__ wk,
                                                   const float* __restrict__ wv,
                                                   const float* __restrict__ bq,
                                                   const float* __restrict__ bk,
                                                   short* __restrict__ x_bf,
                                                   short* __restrict__ w_bf,
                                                   float* __restrict__ bcat) {
  const unsigned gtid = blockIdx.x * 256u + threadIdx.x;   // 524288 threads
  // weights: 786432 float4s (seg boundaries at 262144 -- wave-uniform except
  // at two boundaries; consecutive gtid -> consecutive idx -> coalesced)
#pragma unroll 2
  for (unsigned i = gtid; i < 786432u; i += 524288u) {
    const unsigned seg = i / 262144u, idx = i - seg * 262144u;
    const float* w = seg == 0 ? wq : (seg == 1 ? wk : wv);
    float4v v = ((const float4v*)w)[idx];
    short4v o;
    o.x = f2bf(v.x); o.y = f2bf(v.y); o.z = f2bf(v.z); o.w = f2bf(v.w);
    ((short4v*)(w_bf + (long)seg * 1048576))[idx] = o;
  }
  // x: 2097152 float4s, 4 iters/thread
#pragma unroll 4
  for (unsigned i = gtid; i < 2097152u; i += 524288u) {
    float4v v = ((const float4v*)x)[i];
    short4v o;
    o.x = f2bf(v.x); o.y = f2bf(v.y); o.z = f2bf(v.z); o.w = f2bf(v.w);
    ((short4v*)x_bf)[i] = o;
  }
  if (gtid < 2048u) bcat[gtid] = gtid < 1024u ? bq[gtid] : bk[gtid - 1024u];
}

// ---------- staging: one 128x64 bf16 half-tile, 2 x global_load_lds per thread ----
// LDS layout per row r (128 B): 16B chunk slot s holds global chunk s ^ (r&7).
__device__ __forceinline__ void stage_half(const short* __restrict__ g, int ld,
                                           int grow0, int kt, short* lds, int t) {
  const int r = t >> 3;                         // 0..63
  const int cch = (t & 7) ^ (r & 7);            // global chunk for this slot
  const long co = (long)kt + cch * 8;
  gl2lds16(g + (long)(grow0 + r) * ld + co, lds + t * 8);
  gl2lds16(g + (long)(grow0 + 64 + r) * ld + co, lds + 4096 + t * 8);
}

// ---------- shared GEMM body: C[m,n] = sum_k A[m,k]*B[n,k], BK=64 ----
// MH = number of 128-row A halves. Tile = (128*MH) x 256. 512 threads.
// 8 waves: wm = (wave>>2)*64*MH rows, wn = (wave&3)*64 cols per wave.
// MH=2 (R11/R13-proven, 66us): A 3 slots (rot mod 3), B 2 slots (parity).
//   4 phases, one barrier each; A(k+2) staged P1/P2 (dead slot), B(k+2)
//   staged P3/P4 into live-parity slot (all B reads lgkm-complete before
//   P3's barrier); vmcnt(8) end-P4 drains A(k+1)+B(k+1).
// MH=1 (R12-proven): A 3 slots, B 2 slots. 2 phases:
//   P1: read a+b0 [12]; stage A(k+2); bar; MFMA j0-1
//   P2: read b1 [4]; stage Blo+Bhi(k+2) into live parity; vmcnt(6); bar; MFMA
// EPI 0: +aux[n], store bf16.
// EPI 1: store bf16 exp(v*scale + aux[m*N+n]); partial row sums ->
//        rsum[(wave&3)*8192 + m] (32 slots per (batch,row) total).
// EPI 2: rowsums = sum of 32 partials aux[p*8192+m]; store fp32 v * rcp(rowsum).
// EPI 3: +aux[m], store bf16.
// All pointers pre-offset per batch by the caller.
template <int EPI, int MH>
__device__ __forceinline__ void gemm_body(const short* __restrict__ A,
                                          const short* __restrict__ Bm,
                                          void* __restrict__ C,
                                          const float* __restrict__ aux,
                                          float* __restrict__ rsum, float scale,
                                          int N, int Kd, int Bld, int m0, int n0,
                                          short (*As)[64], short (*Bs)[64]) {
  const int t = threadIdx.x;
  const int lane = t & 63;
  const int wave = t >> 6;               // 0..7
  const int wm = (wave >> 2) * 64 * MH;  // MH=2: 0/128; MH=1: 0/64
  const int wn = (wave & 3) * 64;        // 0,64,128,192
  const int col = lane & 15, quad = lane >> 4;
  const int sw = col & 7;                // reader swizzle (row&7 == col&7)
  const int NT = Kd >> 6;
  constexpr int AS = 128 * MH;           // A slot size in rows

  float4v acc[4 * MH][4] = {};

  // prologue: tiles 0 and 1, A and B
  stage_half(A, Kd, m0, 0, &As[0][0], t);
  if constexpr (MH == 2) stage_half(A, Kd, m0 + 128, 0, &As[128][0], t);
  stage_half(Bm, Bld, n0, 0, &Bs[0][0], t);
  stage_half(Bm, Bld, n0 + 128, 0, &Bs[128][0], t);
  if (NT > 1) {
    stage_half(A, Kd, m0, 64, &As[AS][0], t);
    if constexpr (MH == 2) stage_half(A, Kd, m0 + 128, 64, &As[AS + 128][0], t);
    stage_half(Bm, Bld, n0, 64, &Bs[256][0], t);
    stage_half(Bm, Bld, n0 + 128, 64, &Bs[384][0], t);
    if constexpr (MH == 2)
      asm volatile("s_waitcnt vmcnt(8)" ::: "memory");  // tile0's 8 loads done
    else
      asm volatile("s_waitcnt vmcnt(6)" ::: "memory");  // tile0's 6 loads done
  } else {
    asm volatile("s_waitcnt vmcnt(0)" ::: "memory");
  }
  __builtin_amdgcn_s_barrier();

  int ar = 0;       // A read slot row-offset (slot k%3)
  int aw = 2 * AS;  // A stage slot row-offset (slot (k+2)%3)
  int br = 0;       // B read offset: 0,256 (parity k&1); stage target = br

  for (int k = 0; k < NT; ++k) {
    short8 a[4][2], b0[2][2], b1[2][2];

    if constexpr (MH == 2) {
      // ---------------- P1 ----------------
#pragma unroll
      for (int i = 0; i < 4; ++i)
#pragma unroll
        for (int s = 0; s < 2; ++s)
          a[i][s] = *(const short8*)&As[ar + wm + i * 16 + col][(((s * 4 + quad) ^ sw)) * 8];
#pragma unroll
      for (int j = 0; j < 2; ++j)
#pragma unroll
        for (int s = 0; s < 2; ++s)
          b0[j][s] = *(const short8*)&Bs[br + wn + j * 16 + col][(((s * 4 + quad) ^ sw)) * 8];
      if (k + 2 < NT) stage_half(A, Kd, m0, (k + 2) * 64, &As[aw][0], t);
      __builtin_amdgcn_s_barrier();
      __builtin_amdgcn_s_setprio(1);
#pragma unroll
      for (int i = 0; i < 4; ++i)
#pragma unroll
        for (int j = 0; j < 2; ++j)
#pragma unroll
          for (int s = 0; s < 2; ++s)
            acc[i][j] = __builtin_amdgcn_mfma_f32_16x16x32_bf16(a[i][s], b0[j][s], acc[i][j], 0, 0, 0);
      __builtin_amdgcn_s_setprio(0);

      // ---------------- P2 ----------------
#pragma unroll
      for (int j = 0; j < 2; ++j)
#pragma unroll
        for (int s = 0; s < 2; ++s)
          b1[j][s] = *(const short8*)&Bs[br + wn + (j + 2) * 16 + col][(((s * 4 + quad) ^ sw)) * 8];
      if (k + 2 < NT) stage_half(A, Kd, m0 + 128, (k + 2) * 64, &As[aw + 128][0], t);
      __builtin_amdgcn_s_barrier();
      __builtin_amdgcn_s_setprio(1);
#pragma unroll
      for (int i = 0; i < 4; ++i)
#pragma unroll
        for (int j = 0; j < 2; ++j)
#pragma unroll
          for (int s = 0; s < 2; ++s)
            acc[i][j + 2] = __builtin_amdgcn_mfma_f32_16x16x32_bf16(a[i][s], b1[j][s], acc[i][j + 2], 0, 0, 0);
      __builtin_amdgcn_s_setprio(0);

      // ---------------- P3 ----------------
#pragma unroll
      for (int i = 0; i < 4; ++i)
#pragma unroll
        for (int s = 0; s < 2; ++s)
          a[i][s] = *(const short8*)&As[ar + wm + (i + 4) * 16 + col][(((s * 4 + quad) ^ sw)) * 8];
      if (k + 2 < NT) stage_half(Bm, Bld, n0, (k + 2) * 64, &Bs[br][0], t);
      __builtin_amdgcn_s_barrier();
      __builtin_amdgcn_s_setprio(1);
#pragma unroll
      for (int i = 0; i < 4; ++i)
#pragma unroll
        for (int j = 0; j < 2; ++j)
#pragma unroll
          for (int s = 0; s < 2; ++s)
            acc[i + 4][j + 2] = __builtin_amdgcn_mfma_f32_16x16x32_bf16(a[i][s], b1[j][s], acc[i + 4][j + 2], 0, 0, 0);
      __builtin_amdgcn_s_setprio(0);

      // ---------------- P4 ----------------
      if (k + 2 < NT) stage_half(Bm, Bld, n0 + 128, (k + 2) * 64, &Bs[br + 128][0], t);
      if (k + 2 < NT) {
        asm volatile("s_waitcnt vmcnt(8)" ::: "memory");   // A(k+1)+B(k+1) landed
      } else if (k + 1 < NT) {
        asm volatile("s_waitcnt vmcnt(0)" ::: "memory");   // drain the last tile
      }
      __builtin_amdgcn_s_barrier();
      __builtin_amdgcn_s_setprio(1);
#pragma unroll
      for (int i = 0; i < 4; ++i)
#pragma unroll
        for (int j = 0; j < 2; ++j)
#pragma unroll
          for (int s = 0; s < 2; ++s)
            acc[i + 4][j] = __builtin_amdgcn_mfma_f32_16x16x32_bf16(a[i][s], b0[j][s], acc[i + 4][j], 0, 0, 0);
      __builtin_amdgcn_s_setprio(0);
    } else {
      // ================ MH == 1 (R12 form): 2 phases ================
      // ---------------- P1 ----------------
#pragma unroll
      for (int i = 0; i < 4; ++i)
#pragma unroll
        for (int s = 0; s < 2; ++s)
          a[i][s] = *(const short8*)&As[ar + wm + i * 16 + col][(((s * 4 + quad) ^ sw)) * 8];
#pragma unroll
      for (int j = 0; j < 2; ++j)
#pragma unroll
        for (int s = 0; s < 2; ++s)
          b0[j][s] = *(const short8*)&Bs[br + wn + j * 16 + col][(((s * 4 + quad) ^ sw)) * 8];
      if (k + 2 < NT) stage_half(A, Kd, m0, (k + 2) * 64, &As[aw][0], t);
      __builtin_amdgcn_s_barrier();
      __builtin_amdgcn_s_setprio(1);
#pragma unroll
      for (int i = 0; i < 4; ++i)
#pragma unroll
        for (int j = 0; j < 2; ++j)
#pragma unroll
          for (int s = 0; s < 2; ++s)
            acc[i][j] = __builtin_amdgcn_mfma_f32_16x16x32_bf16(a[i][s], b0[j][s], acc[i][j], 0, 0, 0);
      __builtin_amdgcn_s_setprio(0);

      // ---------------- P2 ----------------
#pragma unroll
      for (int j = 0; j < 2; ++j)
#pragma unroll
        for (int s = 0; s < 2; ++s)
          b1[j][s] = *(const short8*)&Bs[br + wn + (j + 2) * 16 + col][(((s * 4 + quad) ^ sw)) * 8];
      if (k + 2 < NT) {
        stage_half(Bm, Bld, n0, (k + 2) * 64, &Bs[br][0], t);
        stage_half(Bm, Bld, n0 + 128, (k + 2) * 64, &Bs[br + 128][0], t);
        asm volatile("s_waitcnt vmcnt(6)" ::: "memory");   // A(k+1)+B(k+1) landed
      } else if (k + 1 < NT) {
        asm volatile("s_waitcnt vmcnt(0)" ::: "memory");   // drain the last tile
      }
      __builtin_amdgcn_s_barrier();
      __builtin_amdgcn_s_setprio(1);
#pragma unroll
      for (int i = 0; i < 4; ++i)
#pragma unroll
        for (int j = 0; j < 2; ++j)
#pragma unroll
          for (int s = 0; s < 2; ++s)
            acc[i][j + 2] = __builtin_amdgcn_mfma_f32_16x16x32_bf16(a[i][s], b1[j][s], acc[i][j + 2], 0, 0, 0);
      __builtin_amdgcn_s_setprio(0);
    }

    ar = (ar == 2 * AS) ? 0 : ar + AS;
    aw = (aw == 2 * AS) ? 0 : aw + AS;
    br ^= 256;
  }

  // EPI 2: combine the 32 rowsum partials once per block (Bs is free now).
  float* invb = (float*)&Bs[0][0];
  if (EPI == 2) {
    __syncthreads();   // all waves past their last LDS reads before reuse
    if (t < 128 * MH) {
      float s = 0.f;
#pragma unroll
      for (int p = 0; p < 32; ++p) s += aux[p * 8192 + m0 + t];
      invb[t] = __builtin_amdgcn_rcpf(s);
    }
    __syncthreads();
  }

  // C/D layout: col = lane&15, row = quad*4 + reg  (m89-verified)
  const float LOG2E = 1.44269504f;
  const float c1 = scale * LOG2E;
#pragma unroll
  for (int i = 0; i < 4 * MH; ++i) {
    float invv[4], addm[4], rsum4[4] = {0.f, 0.f, 0.f, 0.f};
    if (EPI == 2) {
#pragma unroll
      for (int r = 0; r < 4; ++r) invv[r] = invb[wm + i * 16 + quad * 4 + r];
    }
    if (EPI == 3) {
#pragma unroll
      for (int r = 0; r < 4; ++r) addm[r] = aux[m0 + wm + i * 16 + quad * 4 + r];
    }
#pragma unroll
    for (int j = 0; j < 4; ++j) {
      const int n = n0 + wn + j * 16 + col;
      float addn = 0.f;
      if (EPI == 0) addn = aux[n];
#pragma unroll
      for (int r = 0; r < 4; ++r) {
        const int m = m0 + wm + i * 16 + quad * 4 + r;
        float v = acc[i][j][r];
        if (EPI == 0) {
          ((short*)C)[(long)m * N + n] = f2bf(v + addn);
        } else if (EPI == 1) {
          float mv = aux[(long)m * N + n];
          float e = exp2f(fmaf(v, c1, mv * LOG2E));  // exp(v*scale+mask); |s|~3, safe
          short q = f2bf(e);
          ((short*)C)[(long)m * N + n] = q;
          rsum4[r] += bf2f(q);  // sum exactly what PV will read
        } else if (EPI == 2) {
          ((float*)C)[(long)m * N + n] = v * invv[r];
        } else {
          ((short*)C)[(long)m * N + n] = f2bf(v + addm[r]);
        }
      }
    }
    if (EPI == 1) {
      // reduce across the 16 lanes of this quad-group; one slot per wave-n-quarter
#pragma unroll
      for (int r = 0; r < 4; ++r) {
        float s = rsum4[r];
        s += __shfl_xor(s, 1);
        s += __shfl_xor(s, 2);
        s += __shfl_xor(s, 4);
        s += __shfl_xor(s, 8);
        if (col == 0)
          rsum[(wave & 3) * 8192 + m0 + wm + i * 16 + quad * 4 + r] = s;
      }
    }
  }
}

// ---------- QK interleaved (g<256: bz=g&1 shares x panel) + Vt (g>=256) ----------
__global__ __launch_bounds__(512, 2) void qkv_kernel(const short* __restrict__ x_bf,
                                                     const short* __restrict__ w_bf,
                                                     short* __restrict__ QK,
                                                     short* __restrict__ Vt,
                                                     const float* __restrict__ bcat,
                                                     const float* __restrict__ bv) {
  __shared__ alignas(16) short As[768][64];   // [3 slots][256][64]
  __shared__ alignas(16) short Bs[512][64];   // [2 slots][256][64]
  const int b = blockIdx.x;                   // 384
  const int g = (b & 7) * 48 + (b >> 3);      // bijective (384 % 8 == 0)
  if (g < 256) {
    // Q/K interleave: consecutive same-XCD blocks = (Q,m,n),(K,m,n) -> shared
    // x A-panel in L2.
    const int pair = g >> 1, bz = g & 1;      // 32 m-tiles x 4 n-tiles
    const int m0 = (pair >> 2) * 256, n0 = (pair & 3) * 256;
    gemm_body<0, 2>(x_bf, w_bf + (long)bz * 1048576, QK + (long)bz * 8388608,
                    bcat + bz * 1024, nullptr, 1.f, 1024, 1024, 1024, m0, n0, As, Bs);
  } else {
    const int v = g - 256;                    // 4 m-tiles x 32 n-tiles
    const int m0 = (v >> 5) * 256, n0 = (v & 31) * 256;
    gemm_body<3, 2>(w_bf + 2097152, x_bf, Vt, bv, nullptr, 1.f,
                    8192, 1024, 1024, m0, n0, As, Bs);
  }
}

// ---------- P = exp(Q K^T /32 + mask), partial rowsums -> rspart ----------
__global__ __launch_bounds__(512, 2) void scores_kernel(const short* __restrict__ Q,
                                                        const short* __restrict__ Kb,
                                                        short* __restrict__ P,
                                                        const float* __restrict__ mask,
                                                        float* __restrict__ rspart) {
  __shared__ alignas(16) short As[768][64];
  __shared__ alignas(16) short Bs[512][64];
  const int b = blockIdx.x;                  // 256
  const int g = (b & 7) * 32 + (b >> 3);
  const int bz = g >> 6, t2 = g & 63;        // 8 m-tiles x 8 n-tiles per batch
  const int m0 = (t2 >> 3) * 256, n0 = (t2 & 7) * 256;
  // 4 slots per n-tile (one per wave-n-quarter): 8 n-tiles * 4 = 32 partials/row
  gemm_body<1, 2>(Q + (long)bz * 2097152, Kb + (long)bz * 2097152,
                  P + (long)bz * 4194304, mask,
                  rspart + (long)(n0 >> 8) * 4 * 8192 + bz * 2048, 0.03125f,
                  2048, 1024, 1024, m0, n0, As, Bs);
}

// ---------- out = (P V) / rowsum, 128x256 tiles (R12 form), full round ----------
__global__ __launch_bounds__(512, 2) void pv_kernel(const short* __restrict__ P,
                                                    const short* __restrict__ Vt,
                                                    float* __restrict__ out,
                                                    const float* __restrict__ rspart) {
  __shared__ alignas(16) short As[384][64];   // 3x128 rows (48KB)
  __shared__ alignas(16) short Bs[512][64];   // 2x256 rows (64KB)
  const int b = blockIdx.x;                 // 256
  const int g = (b & 7) * 32 + (b >> 3);
  const int bz = g >> 6, t2 = g & 63;       // 16 m-tiles (128) x 4 n-tiles (256)
  const int m0 = (t2 >> 2) * 128, n0 = (t2 & 3) * 256;
  gemm_body<2, 1>(P + (long)bz * 4194304, Vt + (long)bz * 2048,
                  out + (long)bz * 2097152, rspart + bz * 2048, nullptr, 1.f,
                  1024, 2048, 8192, m0, n0, As, Bs);
}

extern "C" void kernel_launch(void* const* d_in, const int* in_sizes, int n_in,
                              void* d_out, int out_size, void* d_ws, size_t ws_size,
                              hipStream_t stream) {
  const float* x    = (const float*)d_in[0];
  const float* mask = (const float*)d_in[1];
  const float* wq   = (const float*)d_in[2];
  const float* bq   = (const float*)d_in[3];
  const float* wk   = (const float*)d_in[4];
  const float* bk   = (const float*)d_in[5];
  const float* wv   = (const float*)d_in[6];
  const float* bv   = (const float*)d_in[7];
  float* out = (float*)d_out;

  char* ws = (char*)d_ws;
  const size_t MB = 1024 * 1024;
  short* x_bf   = (short*)(ws);             // 16 MB [8192,1024]; dead after qkv
  float* rspart = (float*)(ws);             // 1 MB [32][8192], aliases x_bf
  short* w_bf   = (short*)(ws + 16 * MB);   // 6 MB [3][1024,1024]
  short* QK     = (short*)(ws + 22 * MB);   // 32 MB [2][8192,1024]
  short* Vt     = (short*)(ws + 54 * MB);   // 16 MB [1024][8192] = [d][b*2048+s]
  short* P      = (short*)(ws + 70 * MB);   // 32 MB [4][2048][2048] (unnormalized exp)
  float* bcat   = (float*)(ws + 70 * MB);   // 8 KB, aliases head of P (dead before P)

  // grid-strided prep: 2048 blocks (8/CU), ~5.5 float4s per thread
  prep_kernel<<<2048, 256, 0, stream>>>(x, wq, wk, wv, bq, bk, x_bf, w_bf, bcat);

  // Q,K projections (interleaved) + Vt GEMM, all MH=2, XCD-swizzled
  qkv_kernel<<<384, 512, 0, stream>>>(x_bf, w_bf, QK, Vt, bcat, bv);

  short* Q  = QK;
  short* Kb = QK + 8388608;

  // P = exp(Q K^T / 32 + mask) -> bf16 unnormalized; rspart gets partial sums
  scores_kernel<<<256, 512, 0, stream>>>(Q, Kb, P, mask, rspart);

  // out = (P V) / rowsum, full machine round (R12 measured-best form)
  pv_kernel<<<256, 512, 0, stream>>>(P, Vt, out, rspart);
}